// Round 2
// baseline (1170.403 us; speedup 1.0000x reference)
//
#include <hip/hip_runtime.h>
#include <hip/hip_bf16.h>
#include <climits>

#define B_ 2
#define V_ 4
#define H_ 120
#define W_ 160
#define C_ 96
#define NVOX 200000
#define GRID_ 128
#define NSTEPS 156
#define NRAYS (B_*V_*H_*W_)    // 153600
#define NB1 ((NVOX + 255) / 256)  // 782 scan blocks

// ---------------- Kernel A: per-batch component-wise min of coords ----------
__global__ void shift_kernel(const int* __restrict__ coords, int* __restrict__ shifts) {
    __shared__ int smin[B_ * 3];
    int t = threadIdx.x;
    if (t < B_ * 3) smin[t] = INT_MAX;
    __syncthreads();
    int i = blockIdx.x * blockDim.x + t;
    if (i < NVOX) {
        int b = coords[i * 4 + 0];
        atomicMin(&smin[b * 3 + 0], coords[i * 4 + 1]);
        atomicMin(&smin[b * 3 + 1], coords[i * 4 + 2]);
        atomicMin(&smin[b * 3 + 2], coords[i * 4 + 3]);
    }
    __syncthreads();
    if (t < B_ * 3 && smin[t] != INT_MAX) atomicMin(&shifts[t], smin[t]);
}

// ---------------- Kernel B: build occupancy grid (last-dup wins -> atomicMax)
__global__ void occ_kernel(const int* __restrict__ coords,
                           const int* __restrict__ shifts,
                           int* __restrict__ occ) {
    int i = blockIdx.x * blockDim.x + threadIdx.x;
    if (i >= NVOX) return;
    int b = coords[i * 4 + 0];
    int x = coords[i * 4 + 1] - shifts[b * 3 + 0];
    int y = coords[i * 4 + 2] - shifts[b * 3 + 1];
    int z = coords[i * 4 + 3] - shifts[b * 3 + 2];
    int idx = ((b * GRID_ + z) * GRID_ + y) * GRID_ + x;
    atomicMax(&occ[idx], i);
}

// ---------------- Kernel C: ray march, first hit -> tgt ---------------------
__global__ void march_kernel(const float* __restrict__ vm,
                             const float* __restrict__ intr,
                             const int* __restrict__ shifts,
                             const int* __restrict__ occ,
                             int* __restrict__ tgt) {
    int r = blockIdx.x * blockDim.x + threadIdx.x;
    if (r >= NRAYS) return;
    int w = r % W_;
    int h = (r / W_) % H_;
    int v = (r / (W_ * H_)) % V_;
    int b = r / (W_ * H_ * V_);
    const float* M = vm + (size_t)(b * V_ + v) * 16;
    float fx = intr[0], fy = intr[1], cx = intr[2], cy = intr[3];
    float dx = ((float)w + 0.5f - cx) / fx;
    float dy = ((float)h + 0.5f - cy) / fy;
    float R00 = M[0], R01 = M[1], R02 = M[2];
    float R10 = M[4], R11 = M[5], R12 = M[6];
    float R20 = M[8], R21 = M[9], R22 = M[10];
    float t0 = M[3]  - (float)shifts[b * 3 + 0];
    float t1 = M[7]  - (float)shifts[b * 3 + 1];
    float t2 = M[11] - (float)shifts[b * 3 + 2];
    int res = -1;
    for (int s = 0; s < NSTEPS; ++s) {
        float t = 2.0f + 0.5f * (float)s;
        float px = dx * t, py = dy * t, pz = t;
        float pwx = R00 * px + R01 * py + R02 * pz + t0;
        float pwy = R10 * px + R11 * py + R12 * pz + t1;
        float pwz = R20 * px + R21 * py + R22 * pz + t2;
        int ix = (int)floorf(pwx);
        int iy = (int)floorf(pwy);
        int iz = (int)floorf(pwz);
        if (((unsigned)ix < (unsigned)GRID_) & ((unsigned)iy < (unsigned)GRID_) &
            ((unsigned)iz < (unsigned)GRID_)) {
            int id = occ[((b * GRID_ + iz) * GRID_ + iy) * GRID_ + ix];
            if (id >= 0) { res = id; break; }
        }
    }
    tgt[r] = res;
}

// ---------------- Kernel D: histogram of targets ----------------------------
__global__ void count_kernel(const int* __restrict__ tgt, int* __restrict__ cnt) {
    int r = blockIdx.x * blockDim.x + threadIdx.x;
    if (r >= NRAYS) return;
    int t = tgt[r];
    if (t >= 0) atomicAdd(&cnt[t], 1);
}

// ---------------- Kernel E1: per-block exclusive scan -----------------------
__global__ void scan1_kernel(const int* __restrict__ cnt,
                             int* __restrict__ offs, int* __restrict__ bsum) {
    __shared__ int s[256];
    int tid = threadIdx.x;
    int i = blockIdx.x * 256 + tid;
    int v = (i < NVOX) ? cnt[i] : 0;
    s[tid] = v;
    __syncthreads();
    for (int d = 1; d < 256; d <<= 1) {
        int a = s[tid];
        int u = (tid >= d) ? s[tid - d] : 0;
        __syncthreads();
        s[tid] = a + u;
        __syncthreads();
    }
    if (i < NVOX) offs[i] = s[tid] - v;   // exclusive within block
    if (tid == 255) bsum[blockIdx.x] = s[255];
}

// ---------------- Kernel E2: scan of block sums (single block) --------------
__global__ void scan2_kernel(int* __restrict__ bsum) {
    __shared__ int s[1024];
    int i = threadIdx.x;
    int v = (i < NB1) ? bsum[i] : 0;
    s[i] = v;
    __syncthreads();
    for (int d = 1; d < 1024; d <<= 1) {
        int a = s[i];
        int u = (i >= d) ? s[i - d] : 0;
        __syncthreads();
        s[i] = a + u;
        __syncthreads();
    }
    if (i < NB1) bsum[i] = s[i] - v;      // exclusive
}

// ---------------- Kernel E3: add block offsets ------------------------------
__global__ void scan3_kernel(int* __restrict__ offs, const int* __restrict__ bsum) {
    int i = blockIdx.x * 256 + threadIdx.x;
    if (i < NVOX) offs[i] += bsum[blockIdx.x];
}

// ---------------- Kernel F: bucket rays by target (counting sort) -----------
// After this kernel offs[t] == segment END (start = end - cnt[t]).
__global__ void order_kernel(const int* __restrict__ tgt,
                             int* __restrict__ offs, int* __restrict__ sorted) {
    int r = blockIdx.x * blockDim.x + threadIdx.x;
    if (r >= NRAYS) return;
    int t = tgt[r];
    if (t < 0) return;
    int pos = atomicAdd(&offs[t], 1);
    sorted[pos] = r;
}

// ---------------- Kernel G: wave-per-voxel segmented reduce + finalize ------
__global__ void reduce_kernel(const float* __restrict__ feats,
                              const int* __restrict__ sorted,
                              const int* __restrict__ offs,
                              const int* __restrict__ cnt,
                              float* __restrict__ out,
                              float* __restrict__ cnt_out) {
    int gtid = blockIdx.x * blockDim.x + threadIdx.x;
    int vox  = gtid >> 6;
    int lane = threadIdx.x & 63;
    if (vox >= NVOX) return;
    int c = cnt[vox];
    int start = offs[vox] - c;
    float ax = 0.0f, ay = 0.0f;
    for (int k = 0; k < c; ++k) {
        int r = sorted[start + k];            // broadcast load
        if (lane < 48) {
            const float2* f = (const float2*)(feats + (size_t)r * C_);
            float2 x = f[lane];
            ax += x.x; ay += x.y;
        }
    }
    float denom = (float)c + 0.0001f;
    if (lane < 48) {
        float2* o = (float2*)(out + (size_t)vox * C_);
        float2 w; w.x = ax / denom; w.y = ay / denom;
        o[lane] = w;
    }
    if (lane == 0) cnt_out[vox] = (float)c;
}

extern "C" void kernel_launch(void* const* d_in, const int* in_sizes, int n_in,
                              void* d_out, int out_size, void* d_ws, size_t ws_size,
                              hipStream_t stream) {
    const float* feats  = (const float*)d_in[0];
    const int*   coords = (const int*)d_in[1];
    const float* vm     = (const float*)d_in[2];
    const float* intr   = (const float*)d_in[3];

    float* out     = (float*)d_out;                  // NVOX*C_ floats
    float* cnt_out = out + (size_t)NVOX * C_;        // NVOX floats

    char* ws = (char*)d_ws;
    int* shifts = (int*)ws;                                    // 256 B
    int* cnt    = (int*)(ws + 256);                            // 800,000 B
    int* tgt    = (int*)(ws + 256 + 800000);                   // 614,400 B
    char* occ_base = ws + 256 + 800000 + 614400;
    int* occ    = (int*)occ_base;                              // 33,554,432 B
    // After march_kernel, occ is dead -> alias sort scratch into it.
    int* offs   = (int*)occ_base;                              // 800,000 B
    int* bsum   = (int*)(occ_base + 800000);                   // 3,200 B
    int* sorted = (int*)(occ_base + 803200);                   // 614,400 B

    hipMemsetAsync(shifts, 0x7F, 256, stream);                 // big positive ints
    hipMemsetAsync(cnt, 0, (size_t)NVOX * sizeof(int), stream);
    hipMemsetAsync(occ, 0xFF, (size_t)B_ * GRID_ * GRID_ * GRID_ * sizeof(int), stream); // -1

    shift_kernel<<<(NVOX + 255) / 256, 256, 0, stream>>>(coords, shifts);
    occ_kernel<<<(NVOX + 255) / 256, 256, 0, stream>>>(coords, shifts, occ);
    march_kernel<<<(NRAYS + 255) / 256, 256, 0, stream>>>(vm, intr, shifts, occ, tgt);
    count_kernel<<<(NRAYS + 255) / 256, 256, 0, stream>>>(tgt, cnt);
    scan1_kernel<<<NB1, 256, 0, stream>>>(cnt, offs, bsum);
    scan2_kernel<<<1, 1024, 0, stream>>>(bsum);
    scan3_kernel<<<NB1, 256, 0, stream>>>(offs, bsum);
    order_kernel<<<(NRAYS + 255) / 256, 256, 0, stream>>>(tgt, offs, sorted);
    reduce_kernel<<<(NVOX * 64 + 255) / 256, 256, 0, stream>>>(feats, sorted, offs, cnt,
                                                               out, cnt_out);
}

// Round 3
// 286.750 us; speedup vs baseline: 4.0816x; 4.0816x over previous
//
#include <hip/hip_runtime.h>
#include <hip/hip_bf16.h>
#include <climits>

#define B_ 2
#define V_ 4
#define H_ 120
#define W_ 160
#define C_ 96
#define NVOX 200000
#define GRID_ 128
#define NSTEPS 156
#define NRAYS (B_*V_*H_*W_)       // 153600
#define NB1 ((NVOX + 255) / 256)  // 782 scan blocks
#define CHUNK 32                  // sorted-list entries per wave in chunk_reduce
#define NCHUNK ((NRAYS + CHUNK - 1) / CHUNK)  // 4800 max chunks

// ---------------- Kernel A: per-batch component-wise min of coords ----------
__global__ void shift_kernel(const int* __restrict__ coords, int* __restrict__ shifts) {
    __shared__ int smin[B_ * 3];
    int t = threadIdx.x;
    if (t < B_ * 3) smin[t] = INT_MAX;
    __syncthreads();
    int i = blockIdx.x * blockDim.x + t;
    if (i < NVOX) {
        int b = coords[i * 4 + 0];
        atomicMin(&smin[b * 3 + 0], coords[i * 4 + 1]);
        atomicMin(&smin[b * 3 + 1], coords[i * 4 + 2]);
        atomicMin(&smin[b * 3 + 2], coords[i * 4 + 3]);
    }
    __syncthreads();
    if (t < B_ * 3 && smin[t] != INT_MAX) atomicMin(&shifts[t], smin[t]);
}

// ---------------- Kernel B: build occupancy grid (last-dup wins -> atomicMax)
__global__ void occ_kernel(const int* __restrict__ coords,
                           const int* __restrict__ shifts,
                           int* __restrict__ occ) {
    int i = blockIdx.x * blockDim.x + threadIdx.x;
    if (i >= NVOX) return;
    int b = coords[i * 4 + 0];
    int x = coords[i * 4 + 1] - shifts[b * 3 + 0];
    int y = coords[i * 4 + 2] - shifts[b * 3 + 1];
    int z = coords[i * 4 + 3] - shifts[b * 3 + 2];
    int idx = ((b * GRID_ + z) * GRID_ + y) * GRID_ + x;
    atomicMax(&occ[idx], i);
}

// ---------------- Kernel C: ray march (8-step load groups) + count ----------
__global__ void march_kernel(const float* __restrict__ vm,
                             const float* __restrict__ intr,
                             const int* __restrict__ shifts,
                             const int* __restrict__ occ,
                             int* __restrict__ tgt,
                             int* __restrict__ cnt) {
    int r = blockIdx.x * blockDim.x + threadIdx.x;
    if (r >= NRAYS) return;
    int w = r % W_;
    int h = (r / W_) % H_;
    int v = (r / (W_ * H_)) % V_;
    int b = r / (W_ * H_ * V_);
    const float* M = vm + (size_t)(b * V_ + v) * 16;
    float fx = intr[0], fy = intr[1], cx = intr[2], cy = intr[3];
    float dx = ((float)w + 0.5f - cx) / fx;
    float dy = ((float)h + 0.5f - cy) / fy;
    float R00 = M[0], R01 = M[1], R02 = M[2];
    float R10 = M[4], R11 = M[5], R12 = M[6];
    float R20 = M[8], R21 = M[9], R22 = M[10];
    float t0 = M[3]  - (float)shifts[b * 3 + 0];
    float t1 = M[7]  - (float)shifts[b * 3 + 1];
    float t2 = M[11] - (float)shifts[b * 3 + 2];
    int res = -1;
    for (int g = 0; g < NSTEPS && res < 0; g += 8) {
        int val[8];
        bool ok[8];
#pragma unroll
        for (int j = 0; j < 8; ++j) {
            int st = g + j;
            float t = 2.0f + 0.5f * (float)st;
            float px = dx * t, py = dy * t, pz = t;
            float pwx = R00 * px + R01 * py + R02 * pz + t0;
            float pwy = R10 * px + R11 * py + R12 * pz + t1;
            float pwz = R20 * px + R21 * py + R22 * pz + t2;
            int ix = (int)floorf(pwx);
            int iy = (int)floorf(pwy);
            int iz = (int)floorf(pwz);
            bool ib = ((unsigned)ix < (unsigned)GRID_) &
                      ((unsigned)iy < (unsigned)GRID_) &
                      ((unsigned)iz < (unsigned)GRID_) & (st < NSTEPS);
            int cix = min(max(ix, 0), GRID_ - 1);
            int ciy = min(max(iy, 0), GRID_ - 1);
            int ciz = min(max(iz, 0), GRID_ - 1);
            val[j] = occ[((b * GRID_ + ciz) * GRID_ + ciy) * GRID_ + cix];
            ok[j] = ib;
        }
#pragma unroll
        for (int j = 0; j < 8; ++j)
            if (res < 0 && ok[j] && val[j] >= 0) res = val[j];
    }
    tgt[r] = res;
    if (res >= 0) atomicAdd(&cnt[res], 1);
}

// ---------------- Kernel E1: per-block exclusive scan -----------------------
__global__ void scan1_kernel(const int* __restrict__ cnt,
                             int* __restrict__ offs, int* __restrict__ bsum) {
    __shared__ int s[256];
    int tid = threadIdx.x;
    int i = blockIdx.x * 256 + tid;
    int v = (i < NVOX) ? cnt[i] : 0;
    s[tid] = v;
    __syncthreads();
    for (int d = 1; d < 256; d <<= 1) {
        int a = s[tid];
        int u = (tid >= d) ? s[tid - d] : 0;
        __syncthreads();
        s[tid] = a + u;
        __syncthreads();
    }
    if (i < NVOX) offs[i] = s[tid] - v;   // exclusive within block
    if (tid == 255) bsum[blockIdx.x] = s[255];
}

// ---------------- Kernel E2: scan of block sums + grand total ---------------
__global__ void scan2_kernel(int* __restrict__ bsum) {
    __shared__ int s[1024];
    int i = threadIdx.x;
    int v = (i < NB1) ? bsum[i] : 0;
    s[i] = v;
    __syncthreads();
    for (int d = 1; d < 1024; d <<= 1) {
        int a = s[i];
        int u = (i >= d) ? s[i - d] : 0;
        __syncthreads();
        s[i] = a + u;
        __syncthreads();
    }
    if (i < NB1) bsum[i] = s[i] - v;          // exclusive
    if (i == NB1 - 1) bsum[NB1] = s[i];       // grand total (hit count)
}

// ---------------- Kernel E3: add block offsets ------------------------------
__global__ void scan3_kernel(int* __restrict__ offs, const int* __restrict__ bsum) {
    int i = blockIdx.x * 256 + threadIdx.x;
    if (i < NVOX) offs[i] += bsum[blockIdx.x];
}

// ---------------- Kernel F: bucket rays by target (counting sort) -----------
// After this kernel offs[t] == segment END (start = end - cnt[t]).
__global__ void order_kernel(const int* __restrict__ tgt,
                             int* __restrict__ offs, int2* __restrict__ sorted_rt) {
    int r = blockIdx.x * blockDim.x + threadIdx.x;
    if (r >= NRAYS) return;
    int t = tgt[r];
    if (t < 0) return;
    int pos = atomicAdd(&offs[t], 1);
    sorted_rt[pos] = make_int2(r, t);
}

// ---------------- run flush helper ------------------------------------------
__device__ __forceinline__ void flush_run(int t, float ax, float ay, int lane,
                                          const int* __restrict__ offs,
                                          const int* __restrict__ cnt,
                                          float* __restrict__ out,
                                          float* __restrict__ cnt_out) {
    int c = cnt[t];
    int e = offs[t];
    int s = e - c;
    bool complete = (s / CHUNK) == ((e - 1) / CHUNK);  // segment within one chunk
    if (complete) {
        float denom = (float)c + 0.0001f;
        if (lane < 48) {
            float2 wv; wv.x = ax / denom; wv.y = ay / denom;
            ((float2*)(out + (size_t)t * C_))[lane] = wv;
        }
        if (lane == 0) cnt_out[t] = (float)c;
    } else if (lane < 48) {
        unsafeAtomicAdd(out + (size_t)t * C_ + 2 * lane,     ax);
        unsafeAtomicAdd(out + (size_t)t * C_ + 2 * lane + 1, ay);
    }
}

// ---------------- Kernel G: load-balanced chunked segmented reduce ----------
__global__ void chunk_reduce_kernel(const float* __restrict__ feats,
                                    const int2* __restrict__ sorted_rt,
                                    const int* __restrict__ offs,
                                    const int* __restrict__ cnt,
                                    const int* __restrict__ total_p,
                                    float* __restrict__ out,
                                    float* __restrict__ cnt_out) {
    int wave = (blockIdx.x * blockDim.x + threadIdx.x) >> 6;
    int lane = threadIdx.x & 63;
    int total = total_p[0];
    int a = wave * CHUNK;
    if (a >= total) return;
    int b = min(a + CHUNK, total);
    float ax = 0.0f, ay = 0.0f;
    int cur = -1;
    int2 rt = sorted_rt[a];
    for (int k = a; k < b; ++k) {
        int2 nrt = (k + 1 < b) ? sorted_rt[k + 1] : rt;   // prefetch
        if (rt.y != cur) {
            if (cur >= 0) flush_run(cur, ax, ay, lane, offs, cnt, out, cnt_out);
            cur = rt.y; ax = 0.0f; ay = 0.0f;
        }
        if (lane < 48) {
            float2 x = ((const float2*)(feats + (size_t)rt.x * C_))[lane];
            ax += x.x; ay += x.y;
        }
        rt = nrt;
    }
    flush_run(cur, ax, ay, lane, offs, cnt, out, cnt_out);
}

// ---------------- Kernel H: fixup (divide crossing voxels, zero empties) ----
__global__ void finalize_kernel(const int* __restrict__ offs,
                                const int* __restrict__ cnt,
                                float* __restrict__ out,
                                float* __restrict__ cnt_out) {
    int vox  = (blockIdx.x * blockDim.x + threadIdx.x) >> 6;
    int lane = threadIdx.x & 63;
    if (vox >= NVOX) return;
    int c = cnt[vox];
    if (c == 0) {
        if (lane < 48) {
            float2 z; z.x = 0.0f; z.y = 0.0f;
            ((float2*)(out + (size_t)vox * C_))[lane] = z;
        }
        if (lane == 0) cnt_out[vox] = 0.0f;
        return;
    }
    int e = offs[vox], s = e - c;
    if (s / CHUNK == (e - 1) / CHUNK) return;   // complete: chunk kernel wrote it
    float denom = (float)c + 0.0001f;
    if (lane < 48) {
        float2* o = (float2*)(out + (size_t)vox * C_);
        float2 x = o[lane];
        x.x /= denom; x.y /= denom;
        o[lane] = x;
    }
    if (lane == 0) cnt_out[vox] = (float)c;
}

extern "C" void kernel_launch(void* const* d_in, const int* in_sizes, int n_in,
                              void* d_out, int out_size, void* d_ws, size_t ws_size,
                              hipStream_t stream) {
    const float* feats  = (const float*)d_in[0];
    const int*   coords = (const int*)d_in[1];
    const float* vm     = (const float*)d_in[2];
    const float* intr   = (const float*)d_in[3];

    float* out     = (float*)d_out;                  // NVOX*C_ floats
    float* cnt_out = out + (size_t)NVOX * C_;        // NVOX floats

    char* ws = (char*)d_ws;
    int* shifts = (int*)ws;                                    // 256 B
    int* cnt    = (int*)(ws + 256);                            // 800,000 B
    int* tgt    = (int*)(ws + 256 + 800000);                   // 614,400 B
    char* occ_base = ws + 256 + 800000 + 614400;
    int* occ    = (int*)occ_base;                              // 33,554,432 B
    // After march_kernel, occ is dead -> alias sort scratch into it.
    int* offs      = (int*)occ_base;                           // 800,000 B
    int* bsum      = (int*)(occ_base + 800000);                // (NB1+1)*4 B
    int2* sorted_rt = (int2*)(occ_base + 803200 + 64);         // 1,228,800 B

    hipMemsetAsync(shifts, 0x7F, 256, stream);                 // big positive ints
    hipMemsetAsync(cnt, 0, (size_t)NVOX * sizeof(int), stream);
    hipMemsetAsync(occ, 0xFF, (size_t)B_ * GRID_ * GRID_ * GRID_ * sizeof(int), stream); // -1
    // crossing-segment partial sums accumulate atomically into out -> zero it
    hipMemsetAsync(out, 0, (size_t)NVOX * C_ * sizeof(float), stream);

    shift_kernel<<<(NVOX + 255) / 256, 256, 0, stream>>>(coords, shifts);
    occ_kernel<<<(NVOX + 255) / 256, 256, 0, stream>>>(coords, shifts, occ);
    march_kernel<<<(NRAYS + 255) / 256, 256, 0, stream>>>(vm, intr, shifts, occ, tgt, cnt);
    scan1_kernel<<<NB1, 256, 0, stream>>>(cnt, offs, bsum);
    scan2_kernel<<<1, 1024, 0, stream>>>(bsum);
    scan3_kernel<<<NB1, 256, 0, stream>>>(offs, bsum);
    order_kernel<<<(NRAYS + 255) / 256, 256, 0, stream>>>(tgt, offs, sorted_rt);
    chunk_reduce_kernel<<<(NCHUNK * 64 + 255) / 256, 256, 0, stream>>>(
        feats, sorted_rt, offs, cnt, bsum + NB1, out, cnt_out);
    finalize_kernel<<<((size_t)NVOX * 64 + 255) / 256, 256, 0, stream>>>(
        offs, cnt, out, cnt_out);
}

// Round 4
// 264.160 us; speedup vs baseline: 4.4307x; 1.0855x over previous
//
#include <hip/hip_runtime.h>
#include <hip/hip_bf16.h>
#include <climits>

#define B_ 2
#define V_ 4
#define H_ 120
#define W_ 160
#define C_ 96
#define NVOX 200000
#define GRID_ 128
#define NSTEPS 156
#define NRAYS (B_*V_*H_*W_)       // 153600
#define NB1 ((NVOX + 255) / 256)  // 782 scan blocks
#define CHUNK 32                  // sorted-list entries per wave in chunk_reduce
#define NCHUNK ((NRAYS + CHUNK - 1) / CHUNK)  // 4800 max chunks
#define PARR 4                    // lanes cooperating per ray in march

// ---------------- Kernel A: per-batch component-wise min of coords ----------
__global__ void shift_kernel(const int* __restrict__ coords, int* __restrict__ shifts) {
    __shared__ int smin[B_ * 3];
    int t = threadIdx.x;
    if (t < B_ * 3) smin[t] = INT_MAX;
    __syncthreads();
    int i = blockIdx.x * blockDim.x + t;
    if (i < NVOX) {
        int b = coords[i * 4 + 0];
        atomicMin(&smin[b * 3 + 0], coords[i * 4 + 1]);
        atomicMin(&smin[b * 3 + 1], coords[i * 4 + 2]);
        atomicMin(&smin[b * 3 + 2], coords[i * 4 + 3]);
    }
    __syncthreads();
    if (t < B_ * 3 && smin[t] != INT_MAX) atomicMin(&shifts[t], smin[t]);
}

// ---------------- Kernel B: build occupancy grid (last-dup wins -> atomicMax)
__global__ void occ_kernel(const int* __restrict__ coords,
                           const int* __restrict__ shifts,
                           int* __restrict__ occ) {
    int i = blockIdx.x * blockDim.x + threadIdx.x;
    if (i >= NVOX) return;
    int b = coords[i * 4 + 0];
    int x = coords[i * 4 + 1] - shifts[b * 3 + 0];
    int y = coords[i * 4 + 2] - shifts[b * 3 + 1];
    int z = coords[i * 4 + 3] - shifts[b * 3 + 2];
    int idx = ((b * GRID_ + z) * GRID_ + y) * GRID_ + x;
    atomicMax(&occ[idx], i);
}

// ---------------- Kernel C: step-parallel ray march (4 lanes/ray) -----------
// Lanes 4r..4r+3 cover a 32-step window per round (8 strided steps each);
// first hit = min of (step<<18 | id) over the group.
__global__ void march_kernel(const float* __restrict__ vm,
                             const float* __restrict__ intr,
                             const int* __restrict__ shifts,
                             const int* __restrict__ occ,
                             int* __restrict__ tgt,
                             int* __restrict__ cnt) {
    int gt = blockIdx.x * blockDim.x + threadIdx.x;
    int r = gt >> 2;
    int sub = gt & 3;
    if (r >= NRAYS) return;
    int w = r % W_;
    int h = (r / W_) % H_;
    int v = (r / (W_ * H_)) % V_;
    int b = r / (W_ * H_ * V_);
    const float* M = vm + (size_t)(b * V_ + v) * 16;
    float fx = intr[0], fy = intr[1], cx = intr[2], cy = intr[3];
    float dx = ((float)w + 0.5f - cx) / fx;
    float dy = ((float)h + 0.5f - cy) / fy;
    float R00 = M[0], R01 = M[1], R02 = M[2];
    float R10 = M[4], R11 = M[5], R12 = M[6];
    float R20 = M[8], R21 = M[9], R22 = M[10];
    float t0 = M[3]  - (float)shifts[b * 3 + 0];
    float t1 = M[7]  - (float)shifts[b * 3 + 1];
    float t2 = M[11] - (float)shifts[b * 3 + 2];
    const int MISS = 0x7FFFFFFF;
    int best = MISS;
    for (int w0 = 0; w0 < NSTEPS; w0 += 32) {
        int val[8]; bool ok[8];
#pragma unroll
        for (int j = 0; j < 8; ++j) {
            int st = w0 + sub + 4 * j;
            float t = 2.0f + 0.5f * (float)st;
            float px = dx * t, py = dy * t, pz = t;
            float pwx = R00 * px + R01 * py + R02 * pz + t0;
            float pwy = R10 * px + R11 * py + R12 * pz + t1;
            float pwz = R20 * px + R21 * py + R22 * pz + t2;
            int ix = (int)floorf(pwx);
            int iy = (int)floorf(pwy);
            int iz = (int)floorf(pwz);
            ok[j] = ((unsigned)ix < (unsigned)GRID_) &
                    ((unsigned)iy < (unsigned)GRID_) &
                    ((unsigned)iz < (unsigned)GRID_) & (st < NSTEPS);
            int cix = min(max(ix, 0), GRID_ - 1);
            int ciy = min(max(iy, 0), GRID_ - 1);
            int ciz = min(max(iz, 0), GRID_ - 1);
            val[j] = occ[((b * GRID_ + ciz) * GRID_ + ciy) * GRID_ + cix];
        }
        int local = MISS;
#pragma unroll
        for (int j = 0; j < 8; ++j) {
            int st = w0 + sub + 4 * j;
            if (ok[j] && val[j] >= 0) local = min(local, (st << 18) | val[j]);
        }
        local = min(local, __shfl_xor(local, 1));
        local = min(local, __shfl_xor(local, 2));
        if (local != MISS) { best = local; break; }
    }
    if (sub == 0) {
        int res = (best != MISS) ? (best & 0x3FFFF) : -1;
        tgt[r] = res;
        if (res >= 0) atomicAdd(&cnt[res], 1);
    }
}

// ---------------- Kernel E1: per-block exclusive scan -----------------------
__global__ void scan1_kernel(const int* __restrict__ cnt,
                             int* __restrict__ offs, int* __restrict__ bsum) {
    __shared__ int s[256];
    int tid = threadIdx.x;
    int i = blockIdx.x * 256 + tid;
    int v = (i < NVOX) ? cnt[i] : 0;
    s[tid] = v;
    __syncthreads();
    for (int d = 1; d < 256; d <<= 1) {
        int a = s[tid];
        int u = (tid >= d) ? s[tid - d] : 0;
        __syncthreads();
        s[tid] = a + u;
        __syncthreads();
    }
    if (i < NVOX) offs[i] = s[tid] - v;   // exclusive within block
    if (tid == 255) bsum[blockIdx.x] = s[255];
}

// ---------------- Kernel E2: scan of block sums + grand total ---------------
__global__ void scan2_kernel(int* __restrict__ bsum) {
    __shared__ int s[1024];
    int i = threadIdx.x;
    int v = (i < NB1) ? bsum[i] : 0;
    s[i] = v;
    __syncthreads();
    for (int d = 1; d < 1024; d <<= 1) {
        int a = s[i];
        int u = (i >= d) ? s[i - d] : 0;
        __syncthreads();
        s[i] = a + u;
        __syncthreads();
    }
    if (i < NB1) bsum[i] = s[i] - v;          // exclusive
    if (i == NB1 - 1) bsum[NB1] = s[i];       // grand total (hit count)
}

// ---------------- Kernel E3: add block offsets ------------------------------
__global__ void scan3_kernel(int* __restrict__ offs, const int* __restrict__ bsum) {
    int i = blockIdx.x * 256 + threadIdx.x;
    if (i < NVOX) offs[i] += bsum[blockIdx.x];
}

// ---------------- Kernel F: bucket rays by target (counting sort) -----------
// After this kernel offs[t] == segment END (start = end - cnt[t]).
__global__ void order_kernel(const int* __restrict__ tgt,
                             int* __restrict__ offs, int2* __restrict__ sorted_rt) {
    int r = blockIdx.x * blockDim.x + threadIdx.x;
    if (r >= NRAYS) return;
    int t = tgt[r];
    if (t < 0) return;
    int pos = atomicAdd(&offs[t], 1);
    sorted_rt[pos] = make_int2(r, t);
}

// ---------------- run flush: middle runs need no cnt/offs -------------------
__device__ __forceinline__ void flush_run2(int t, int ks, int ke, int n,
                                           float ax, float ay, int lane,
                                           const int* __restrict__ offs,
                                           const int* __restrict__ cnt,
                                           float* __restrict__ out,
                                           float* __restrict__ cnt_out) {
    int c;
    bool complete;
    if (ks > 0 && ke < n) {          // middle run: whole segment inside chunk
        c = ke - ks;
        complete = true;
    } else {                          // boundary run: consult global segment
        c = cnt[t];
        int e = offs[t];
        int s = e - c;
        complete = (s / CHUNK) == ((e - 1) / CHUNK);
    }
    if (complete) {
        float denom = (float)c + 0.0001f;
        if (lane < 48) {
            float2 wv; wv.x = ax / denom; wv.y = ay / denom;
            ((float2*)(out + (size_t)t * C_))[lane] = wv;
        }
        if (lane == 0) cnt_out[t] = (float)c;
    } else if (lane < 48) {
        unsafeAtomicAdd(out + (size_t)t * C_ + 2 * lane,     ax);
        unsafeAtomicAdd(out + (size_t)t * C_ + 2 * lane + 1, ay);
    }
}

// ---------------- Kernel G: load-balanced chunked segmented reduce ----------
__global__ void chunk_reduce_kernel(const float* __restrict__ feats,
                                    const int2* __restrict__ sorted_rt,
                                    const int* __restrict__ offs,
                                    const int* __restrict__ cnt,
                                    const int* __restrict__ total_p,
                                    float* __restrict__ out,
                                    float* __restrict__ cnt_out) {
    int wave = (blockIdx.x * blockDim.x + threadIdx.x) >> 6;
    int lane = threadIdx.x & 63;
    int total = total_p[0];
    int a = wave * CHUNK;
    if (a >= total) return;
    int n = min(CHUNK, total - a);
    // Preload the whole chunk wave-wide: lane k holds entry a+k.
    int myr = 0, myt = 0;
    if (lane < n) { int2 e = sorted_rt[a + lane]; myr = e.x; myt = e.y; }
    float ax = 0.0f, ay = 0.0f;
    int cur = -1, run_start = 0;
    for (int k0 = 0; k0 < n; k0 += 4) {
        float2 vbuf[4]; int tt[4];
#pragma unroll
        for (int j = 0; j < 4; ++j) {             // issue 4 feature loads
            int k = k0 + j;
            int rr = __shfl(myr, k);
            tt[j]  = __shfl(myt, k);
            vbuf[j] = make_float2(0.0f, 0.0f);
            if (k < n && lane < 48)
                vbuf[j] = ((const float2*)(feats + (size_t)rr * C_))[lane];
        }
#pragma unroll
        for (int j = 0; j < 4; ++j) {             // accumulate with run tracking
            int k = k0 + j;
            if (k >= n) break;
            if (tt[j] != cur) {
                if (cur >= 0)
                    flush_run2(cur, run_start, k, n, ax, ay, lane, offs, cnt, out, cnt_out);
                cur = tt[j]; run_start = k; ax = 0.0f; ay = 0.0f;
            }
            ax += vbuf[j].x; ay += vbuf[j].y;
        }
    }
    flush_run2(cur, run_start, n, n, ax, ay, lane, offs, cnt, out, cnt_out);
}

// ---------------- Kernel H: fixup — divide crossing voxels only -------------
// Empty rows + empty cnt_out are covered by the d_out memset.
__global__ void finalize_kernel(const int* __restrict__ offs,
                                const int* __restrict__ cnt,
                                float* __restrict__ out,
                                float* __restrict__ cnt_out) {
    int vox  = (blockIdx.x * blockDim.x + threadIdx.x) >> 6;
    int lane = threadIdx.x & 63;
    if (vox >= NVOX) return;
    int c = cnt[vox];
    if (c == 0) return;
    int e = offs[vox], s = e - c;
    if (s / CHUNK == (e - 1) / CHUNK) return;   // complete: chunk kernel wrote it
    float denom = (float)c + 0.0001f;
    if (lane < 48) {
        float2* o = (float2*)(out + (size_t)vox * C_);
        float2 x = o[lane];
        x.x /= denom; x.y /= denom;
        o[lane] = x;
    }
    if (lane == 0) cnt_out[vox] = (float)c;
}

extern "C" void kernel_launch(void* const* d_in, const int* in_sizes, int n_in,
                              void* d_out, int out_size, void* d_ws, size_t ws_size,
                              hipStream_t stream) {
    const float* feats  = (const float*)d_in[0];
    const int*   coords = (const int*)d_in[1];
    const float* vm     = (const float*)d_in[2];
    const float* intr   = (const float*)d_in[3];

    float* out     = (float*)d_out;                  // NVOX*C_ floats
    float* cnt_out = out + (size_t)NVOX * C_;        // NVOX floats

    char* ws = (char*)d_ws;
    int* shifts = (int*)ws;                                    // 256 B
    int* cnt    = (int*)(ws + 256);                            // 800,000 B
    int* tgt    = (int*)(ws + 256 + 800000);                   // 614,400 B
    char* occ_base = ws + 256 + 800000 + 614400;
    int* occ    = (int*)occ_base;                              // 33,554,432 B
    // After march_kernel, occ is dead -> alias sort scratch into it.
    int* offs      = (int*)occ_base;                           // 800,000 B
    int* bsum      = (int*)(occ_base + 800000);                // (NB1+1)*4 B
    int2* sorted_rt = (int2*)(occ_base + 803200 + 64);         // 1,228,800 B

    hipMemsetAsync(shifts, 0x7F, 256, stream);                 // big positive ints
    hipMemsetAsync(cnt, 0, (size_t)NVOX * sizeof(int), stream);
    hipMemsetAsync(occ, 0xFF, (size_t)B_ * GRID_ * GRID_ * GRID_ * sizeof(int), stream); // -1
    // zero full output (incl. cnt_out): empties covered; crossing rows start at 0
    hipMemsetAsync(d_out, 0, (size_t)out_size * sizeof(float), stream);

    shift_kernel<<<(NVOX + 255) / 256, 256, 0, stream>>>(coords, shifts);
    occ_kernel<<<(NVOX + 255) / 256, 256, 0, stream>>>(coords, shifts, occ);
    march_kernel<<<(NRAYS * PARR + 255) / 256, 256, 0, stream>>>(vm, intr, shifts, occ, tgt, cnt);
    scan1_kernel<<<NB1, 256, 0, stream>>>(cnt, offs, bsum);
    scan2_kernel<<<1, 1024, 0, stream>>>(bsum);
    scan3_kernel<<<NB1, 256, 0, stream>>>(offs, bsum);
    order_kernel<<<(NRAYS + 255) / 256, 256, 0, stream>>>(tgt, offs, sorted_rt);
    chunk_reduce_kernel<<<(NCHUNK * 64 + 255) / 256, 256, 0, stream>>>(
        feats, sorted_rt, offs, cnt, bsum + NB1, out, cnt_out);
    finalize_kernel<<<((size_t)NVOX * 64 + 255) / 256, 256, 0, stream>>>(
        offs, cnt, out, cnt_out);
}